// Round 12
// baseline (578.008 us; speedup 1.0000x reference)
//
#include <hip/hip_runtime.h>
#include <hip/hip_bf16.h>

#define DIM    16
#define BATCH  32
#define KL     4
#define NTS    512
#define NC     4
#define NPAR   16
#define DTF    (1.0f/512.0f)
#define BST    40     // bf16 operand row stride (ushort) for sP/sL
#define FST    20     // f32 tile row stride
#define TST    36     // paired-u32 T row stride

using short8  = __attribute__((ext_vector_type(8))) short;
using short4v = __attribute__((ext_vector_type(4))) short;
using f32x4   = __attribute__((ext_vector_type(4))) float;

__device__ __forceinline__ float b2f(__hip_bfloat16 x) { return __bfloat162float(x); }

__device__ __forceinline__ float ldval(const void* p, int idx, bool isf32) {
  return isf32 ? ((const float*)p)[idx]
               : __bfloat162float(((const __hip_bfloat16*)p)[idx]);
}
__device__ __forceinline__ unsigned short f2bf(float x) {   // RNE (setup/L only)
  unsigned u = __float_as_uint(x);
  unsigned r = u + 0x7FFFu + ((u >> 16) & 1u);
  return (unsigned short)(r >> 16);
}
__device__ __forceinline__ float bf2f(unsigned short h) {
  return __uint_as_float(((unsigned)h) << 16);
}
// trunc-trunc hi/lo split (R10-verified)
__device__ __forceinline__ void split2(float v, unsigned short& h, unsigned short& l) {
  unsigned u = __float_as_uint(v);
  h = (unsigned short)(u >> 16);
  float r = v - __uint_as_float(u & 0xFFFF0000u);
  l = (unsigned short)(__float_as_uint(r) >> 16);
}
__device__ __forceinline__ unsigned splitpack(float v) {
  unsigned short h, l;
  split2(v, h, l);
  return (unsigned)h | ((unsigned)l << 16);
}
__device__ __forceinline__ short8 ldfrag(const unsigned short* p) {
  return *(const short8*)p;
}
__device__ __forceinline__ short8 negbf8(short8 a) {
  union { short8 s; unsigned u[4]; } v; v.s = a;
  #pragma unroll
  for (int q = 0; q < 4; ++q) v.u[q] ^= 0x80008000u;
  return v.s;
}
__device__ __forceinline__ f32x4 mm3(short8 Ah, short8 Al, short8 Bh, short8 Bl, f32x4 acc) {
  acc = __builtin_amdgcn_mfma_f32_16x16x32_bf16(Ah, Bh, acc, 0, 0, 0);
  acc = __builtin_amdgcn_mfma_f32_16x16x32_bf16(Al, Bh, acc, 0, 0, 0);
  acc = __builtin_amdgcn_mfma_f32_16x16x32_bf16(Ah, Bl, acc, 0, 0, 0);
  return acc;
}
__device__ __forceinline__ void packfrag(const float* v, short8& hi, short8& lo) {
  union { short8 s; unsigned short e[8]; } H, L;
  #pragma unroll
  for (int q = 0; q < 8; ++q) split2(v[q], H.e[q], L.e[q]);
  hi = H.s; lo = L.s;
}
// R11-verified paired-u32 fragment load (hi|lo<<16) via v_perm
__device__ __forceinline__ void ldfrag_paired(const unsigned* p, short8& hi, short8& lo) {
  uint4 wa = *(const uint4*)p;
  uint4 wb = *(const uint4*)(p + 4);
  union { short8 s; unsigned u[4]; } H, L;
  H.u[0] = __builtin_amdgcn_perm(wa.y, wa.x, 0x05040100u);
  H.u[1] = __builtin_amdgcn_perm(wa.w, wa.z, 0x05040100u);
  H.u[2] = __builtin_amdgcn_perm(wb.y, wb.x, 0x05040100u);
  H.u[3] = __builtin_amdgcn_perm(wb.w, wb.z, 0x05040100u);
  L.u[0] = __builtin_amdgcn_perm(wa.y, wa.x, 0x07060302u);
  L.u[1] = __builtin_amdgcn_perm(wa.w, wa.z, 0x07060302u);
  L.u[2] = __builtin_amdgcn_perm(wb.y, wb.x, 0x07060302u);
  L.u[3] = __builtin_amdgcn_perm(wb.w, wb.z, 0x07060302u);
  hi = H.s; lo = L.s;
}

__global__ __launch_bounds__(128, 1)
void lindblad_evolve(const void* __restrict__ g_params,
                     const void* __restrict__ g_H0re, const void* __restrict__ g_H0im,
                     const void* __restrict__ g_Hcre, const void* __restrict__ g_Hcim,
                     const void* __restrict__ g_Lre,  const void* __restrict__ g_Lim,
                     const void* __restrict__ g_r0re, const void* __restrict__ g_r0im,
                     float* __restrict__ g_out)
{
  __shared__ __align__(16) unsigned short sPh[16*BST], sPl[16*BST];         // rho^T' hi/lo
  __shared__ __align__(16) unsigned sTp[KL][16*TST];                        // T'_k paired u32
  __shared__ __align__(16) unsigned short sLh[KL][16*BST], sLl[KL][16*BST]; // L'_k (setup)
  __shared__ __align__(16) float sMr[16*FST], sMi[16*FST];                  // M normal layout
  __shared__ __align__(16) float sU[NTS][NC];
  __shared__ __align__(16) float sPops[NTS*DIM];  // pops; first 2560 f32 = setup G-scratch
  __shared__ int sFlag;

  const int tid = threadIdx.x;       // 0..127 (2 waves)
  const int b   = blockIdx.x;
  const int wv  = tid >> 6;          // 0 = re-wave, 1 = im-wave
  const int ln  = tid & 63;
  const int fm  = ln & 15;
  const int fq  = ln >> 4;
  const int row0 = fq * 4;
  const int fOff  = fm*BST + fq*8;
  const int fOffS = fm*BST + ((fq*8 + 16) & 31);

  // ---- input storage-dtype detection (covers all 256 elems with 128 threads) ----
  if (tid == 0) sFlag = 0;
  __syncthreads();
  {
    float v0 = b2f(((const __hip_bfloat16*)g_H0re)[tid]);
    float v1 = b2f(((const __hip_bfloat16*)g_H0re)[tid + 128]);
    if (!(fabsf(v0) <= 1e10f) || !(fabsf(v1) <= 1e10f)) atomicOr(&sFlag, 1);
  }
  __syncthreads();
  const bool isf32 = (sFlag != 0);

  // ---- B-spline control pulses (4 passes of 128) ----
  {
    float kn[20];
    kn[0] = 0.f; kn[1] = 0.f; kn[2] = 0.f;
    #pragma unroll
    for (int q = 0; q < 14; ++q) kn[3 + q] = (float)q / 13.0f;
    kn[17] = 1.f; kn[18] = 1.f; kn[19] = 1.f;
    for (int ts = tid; ts < NTS; ts += 128) {
      const float t = (float)ts * DTF;
      float B[19];
      #pragma unroll
      for (int q = 0; q < 19; ++q) B[q] = (kn[q] <= t && t < kn[q+1]) ? 1.f : 0.f;
      #pragma unroll
      for (int d = 1; d <= 3; ++d) {
        #pragma unroll
        for (int q = 0; q + d < 19; ++q) {
          float ld = kn[q+d]   - kn[q];
          float rd = kn[q+d+1] - kn[q+1];
          float lv = (ld > 0.f) ? (t - kn[q])     / ld * B[q]   : 0.f;
          float rv = (rd > 0.f) ? (kn[q+d+1] - t) / rd * B[q+1] : 0.f;
          B[q] = lv + rv;
        }
      }
      #pragma unroll
      for (int c = 0; c < NC; ++c) {
        float s = 0.f;
        #pragma unroll
        for (int q = 0; q < NPAR; ++q) s += B[q] * ldval(g_params, q*NC + c, isf32);
        sU[ts][c] = s;
      }
    }
  }

  // ---- constants staging (2 passes of 128 elementwise (i,j)) ----
  for (int e = tid; e < 256; e += 128) {
    float* scr = sPops;   // planes: 0=G0r 1=G0i 2+2c=Gc_r 3+2c=Gc_i
    const int i = e >> 4, j = e & 15;
    const int ij = i*16 + j, ji = j*16 + i;
    float h0r = 0.5f * (ldval(g_H0re, ij, isf32) + ldval(g_H0re, ji, isf32));
    float h0i = 0.5f * (ldval(g_H0im, ij, isf32) - ldval(g_H0im, ji, isf32));
    float ldr = 0.f, ldi = 0.f;
    for (int k = 0; k < KL; ++k) {
      #pragma unroll
      for (int m = 0; m < DIM; ++m) {
        float ar = ldval(g_Lre, k*256 + m*16 + i, isf32), ai = ldval(g_Lim, k*256 + m*16 + i, isf32);
        float br = ldval(g_Lre, k*256 + m*16 + j, isf32), bi = ldval(g_Lim, k*256 + m*16 + j, isf32);
        ldr += ar*br + ai*bi;
        ldi += ar*bi - ai*br;
      }
    }
    scr[0*256 + ij] =  h0i - 0.5f*ldr;   // G0r
    scr[1*256 + ij] = -h0r - 0.5f*ldi;   // G0i
    #pragma unroll
    for (int c = 0; c < NC; ++c) {
      float hr = 0.5f * (ldval(g_Hcre, c*256 + ij, isf32) + ldval(g_Hcre, c*256 + ji, isf32));
      float hi = 0.5f * (ldval(g_Hcim, c*256 + ij, isf32) - ldval(g_Hcim, c*256 + ji, isf32));
      scr[(2 + 2*c)*256 + ij] =  hi;
      scr[(3 + 2*c)*256 + ij] = -hr;
    }
    // L': RNE hi/lo split
    #pragma unroll
    for (int k = 0; k < KL; ++k) {
      float lr = ldval(g_Lre, k*256 + ij, isf32);
      float li = ldval(g_Lim, k*256 + ij, isf32);
      unsigned short h;
      h = f2bf(lr); sLh[k][i*BST + j]      = h; sLl[k][i*BST + j]      = f2bf(lr - bf2f(h));
      h = f2bf(li); sLh[k][i*BST + 16 + j] = h; sLl[k][i*BST + 16 + j] = f2bf(li - bf2f(h));
    }
    // rho^T'(0)
    float r0 = ldval(g_r0re, b*256 + ij, isf32);
    float m0 = ldval(g_r0im, b*256 + ij, isf32);
    unsigned short h, l;
    split2(r0, h, l); sPh[j*BST + i]      = h; sPl[j*BST + i]      = l;
    split2(m0, h, l); sPh[j*BST + 16 + i] = h; sPl[j*BST + 16 + i] = l;
  }

  __syncthreads();   // scratch, sL, sP, sU visible

  // ---- per-wave preloads ----
  float  G0v[8], Gcv[NC][8];          // G fragment constants (both waves)
  short8 Lfh[KL], Lfl[KL];            // straight L' frags: T A-operand (both); wv0 JB too
  short8 JBh[KL], JBl[KL];            // J B-operands: wv0 = straight, wv1 = swap+neg
  short8 Gh, Gl;                      // current G'(t) fragment
  float  rm[4];                       // rho master (C-layout): wv0 = re, wv1 = im
  {
    const int comp = (fq < 2) ? 0 : 1;
    const int base = (fq & 1) * 8;
    const float* scr = sPops;
    {
      const float* s0 = &scr[comp*256 + fm*16 + base];
      f32x4 va = *(const f32x4*)s0, vb = *(const f32x4*)(s0 + 4);
      #pragma unroll
      for (int q = 0; q < 4; ++q) { G0v[q] = va[q]; G0v[4+q] = vb[q]; }
    }
    #pragma unroll
    for (int c = 0; c < NC; ++c) {
      const float* s0 = &scr[(2 + 2*c + comp)*256 + fm*16 + base];
      f32x4 va = *(const f32x4*)s0, vb = *(const f32x4*)(s0 + 4);
      #pragma unroll
      for (int q = 0; q < 4; ++q) { Gcv[c][q] = va[q]; Gcv[c][4+q] = vb[q]; }
    }
    f32x4 uv = *(const f32x4*)&sU[0][0];
    float gv[8];
    #pragma unroll
    for (int q = 0; q < 8; ++q)
      gv[q] = G0v[q] + uv[0]*Gcv[0][q] + uv[1]*Gcv[1][q] + uv[2]*Gcv[2][q] + uv[3]*Gcv[3][q];
    packfrag(gv, Gh, Gl);

    #pragma unroll
    for (int k = 0; k < KL; ++k) { Lfh[k] = ldfrag(&sLh[k][fOff]); Lfl[k] = ldfrag(&sLl[k][fOff]); }
    if (wv == 0) {
      #pragma unroll
      for (int k = 0; k < KL; ++k) { JBh[k] = Lfh[k]; JBl[k] = Lfl[k]; }   // straight (R7-verified)
      #pragma unroll
      for (int q = 0; q < 4; ++q) rm[q] = ldval(g_r0re, b*256 + (row0+q)*16 + fm, isf32);
    } else {
      #pragma unroll
      for (int k = 0; k < KL; ++k) {                                       // swap+neg (R7-verified)
        short8 h = ldfrag(&sLh[k][fOffS]);
        short8 l = ldfrag(&sLl[k][fOffS]);
        if (fq < 2) { h = negbf8(h); l = negbf8(l); }
        JBh[k] = h; JBl[k] = l;
      }
      #pragma unroll
      for (int q = 0; q < 4; ++q) rm[q] = ldval(g_r0im, b*256 + (row0+q)*16 + fm, isf32);
    }
  }

  float* const Mn = (wv == 0) ? sMr : sMi;
  const int toff = (wv == 0) ? 0 : 16;

  // ---- main Euler loop: 2 barriers/step, 2 waves ----
  #pragma unroll 1
  for (int t = 0; t < NTS; ++t) {
    __syncthreads();   // B1: sP(t) visible

    // ---- phase 1: this wave's component of M and all T_k ----
    short8 Bh, Bl;
    if (wv == 0) {
      Bh = ldfrag(&sPh[fOff]);  Bl = ldfrag(&sPl[fOff]);     // Br-type
      if (fq >= 2) { Bh = negbf8(Bh); Bl = negbf8(Bl); }
    } else {
      Bh = ldfrag(&sPh[fOffS]); Bl = ldfrag(&sPl[fOffS]);    // Bi-type
    }
    f32x4 d1 = {0.f,0.f,0.f,0.f};                            // M component (own tile)
    d1 = mm3(Gh, Gl, Bh, Bl, d1);
    f32x4 t0 = {0.f,0.f,0.f,0.f}, t1 = {0.f,0.f,0.f,0.f},
          t2 = {0.f,0.f,0.f,0.f}, t3 = {0.f,0.f,0.f,0.f};
    t0 = mm3(Lfh[0], Lfl[0], Bh, Bl, t0);
    t1 = mm3(Lfh[1], Lfl[1], Bh, Bl, t1);
    t2 = mm3(Lfh[2], Lfl[2], Bh, Bl, t2);
    t3 = mm3(Lfh[3], Lfl[3], Bh, Bl, t3);
    #pragma unroll
    for (int r = 0; r < 4; ++r) Mn[(row0 + r)*FST + fm] = d1[r];
    #pragma unroll
    for (int r = 0; r < 4; ++r) {
      sTp[0][(row0 + r)*TST + toff + fm] = splitpack(t0[r]);
      sTp[1][(row0 + r)*TST + toff + fm] = splitpack(t1[r]);
      sTp[2][(row0 + r)*TST + toff + fm] = splitpack(t2[r]);
      sTp[3][(row0 + r)*TST + toff + fm] = splitpack(t3[r]);
    }
    // rebuild G'(t+1) fragment (registers only)
    {
      const int tn = (t + 1 < NTS) ? (t + 1) : t;
      f32x4 uv = *(const f32x4*)&sU[tn][0];
      float gv[8];
      #pragma unroll
      for (int q = 0; q < 8; ++q)
        gv[q] = G0v[q] + uv[0]*Gcv[0][q] + uv[1]*Gcv[1][q] + uv[2]*Gcv[2][q] + uv[3]*Gcv[3][q];
      packfrag(gv, Gh, Gl);
    }

    __syncthreads();   // B2: sT, sM visible

    // ---- phase 2: J component + update ----
    short8 T0h, T0l, T1h, T1l, T2h, T2l, T3h, T3l;
    ldfrag_paired(&sTp[0][fm*TST + fq*8], T0h, T0l);
    ldfrag_paired(&sTp[1][fm*TST + fq*8], T1h, T1l);
    ldfrag_paired(&sTp[2][fm*TST + fq*8], T2h, T2l);
    ldfrag_paired(&sTp[3][fm*TST + fq*8], T3h, T3l);
    f32x4 a0 = {0.f,0.f,0.f,0.f}, a1 = {0.f,0.f,0.f,0.f},
          a2 = {0.f,0.f,0.f,0.f}, a3 = {0.f,0.f,0.f,0.f};
    a0 = mm3(T0h, T0l, JBh[0], JBl[0], a0);
    a1 = mm3(T1h, T1l, JBh[1], JBl[1], a1);
    a2 = mm3(T2h, T2l, JBh[2], JBl[2], a2);
    a3 = mm3(T3h, T3l, JBh[3], JBl[3], a3);
    f32x4 d2 = *(const f32x4*)&Mn[fm*FST + row0];   // transpose term M[fm][row0+q]
    union { short4v s; unsigned short e[4]; } HH, LL;
    if (wv == 0) {
      #pragma unroll
      for (int q = 0; q < 4; ++q) {
        rm[q] += DTF * (d1[q] + d2[q] + ((a0[q] + a1[q]) + (a2[q] + a3[q])));
        split2(rm[q], HH.e[q], LL.e[q]);
      }
      *(short4v*)&sPh[fm*BST + row0] = HH.s;
      *(short4v*)&sPl[fm*BST + row0] = LL.s;
      if ((unsigned)(fm - row0) < 4u) sPops[t*DIM + fm] = rm[fm - row0];
    } else {
      #pragma unroll
      for (int q = 0; q < 4; ++q) {
        rm[q] += DTF * (d1[q] - d2[q] + ((a0[q] + a1[q]) + (a2[q] + a3[q])));
        split2(rm[q], HH.e[q], LL.e[q]);
      }
      *(short4v*)&sPh[fm*BST + 16 + row0] = HH.s;
      *(short4v*)&sPl[fm*BST + 16 + row0] = LL.s;
    }
  }

  // ---- final coalesced pops flush (float4, 16 iterations) ----
  __syncthreads();
  #pragma unroll
  for (int s = 0; s < NTS*DIM/(128*4); ++s) {
    int idx = (s*128 + tid) * 4;                 // idx = t*16 + d, d 4-aligned
    int tt = idx >> 4, dd = idx & 15;
    *(float4*)&g_out[tt*(BATCH*DIM) + b*DIM + dd] = *(const float4*)&sPops[idx];
  }
}

extern "C" void kernel_launch(void* const* d_in, const int* in_sizes, int n_in,
                              void* d_out, int out_size, void* d_ws, size_t ws_size,
                              hipStream_t stream) {
  (void)out_size; (void)d_ws; (void)ws_size;
  const void *P, *H0r, *H0i, *Hcr, *Hci, *Lr, *Li, *R0r, *R0i;
  int idx64 = -1;
  for (int q = 0; q < n_in; ++q) if (in_sizes[q] == 64) idx64 = q;
  if (idx64 == 6) {   // alphabetical fallback
    H0i = d_in[0]; H0r = d_in[1];
    Hci = d_in[2]; Hcr = d_in[3];
    Li  = d_in[4]; Lr  = d_in[5];
    P   = d_in[6];
    R0i = d_in[7]; R0r = d_in[8];
  } else {            // documented setup_inputs() dict order (R4-verified)
    P   = d_in[0];
    H0r = d_in[1]; H0i = d_in[2];
    Hcr = d_in[3]; Hci = d_in[4];
    Lr  = d_in[5]; Li  = d_in[6];
    R0r = d_in[7]; R0i = d_in[8];
  }
  lindblad_evolve<<<dim3(BATCH), dim3(128), 0, stream>>>(
      P, H0r, H0i, Hcr, Hci, Lr, Li, R0r, R0i, (float*)d_out);
}

// Round 13
// 518.296 us; speedup vs baseline: 1.1152x; 1.1152x over previous
//
#include <hip/hip_runtime.h>
#include <hip/hip_bf16.h>

#define DIM    16
#define BATCH  32
#define KL     4
#define NTS    512
#define NC     4
#define NPAR   16
#define DTF    (1.0f/512.0f)
#define BST    40     // bf16 operand row stride (ushort) for sP/sL
#define FST    20     // f32 tile row stride
#define TST    36     // paired-u32 T row stride

using short8  = __attribute__((ext_vector_type(8))) short;
using short4v = __attribute__((ext_vector_type(4))) short;
using f32x4   = __attribute__((ext_vector_type(4))) float;

__device__ __forceinline__ float b2f(__hip_bfloat16 x) { return __bfloat162float(x); }

__device__ __forceinline__ float ldval(const void* p, int idx, bool isf32) {
  return isf32 ? ((const float*)p)[idx]
               : __bfloat162float(((const __hip_bfloat16*)p)[idx]);
}
__device__ __forceinline__ unsigned short f2bf(float x) {   // RNE (setup/L only)
  unsigned u = __float_as_uint(x);
  unsigned r = u + 0x7FFFu + ((u >> 16) & 1u);
  return (unsigned short)(r >> 16);
}
__device__ __forceinline__ float bf2f(unsigned short h) {
  return __uint_as_float(((unsigned)h) << 16);
}
// trunc-trunc hi/lo split (R10-verified)
__device__ __forceinline__ void split2(float v, unsigned short& h, unsigned short& l) {
  unsigned u = __float_as_uint(v);
  h = (unsigned short)(u >> 16);
  float r = v - __uint_as_float(u & 0xFFFF0000u);
  l = (unsigned short)(__float_as_uint(r) >> 16);
}
__device__ __forceinline__ unsigned splitpack(float v) {    // u32 = hi | lo<<16
  unsigned short h, l;
  split2(v, h, l);
  return (unsigned)h | ((unsigned)l << 16);
}
__device__ __forceinline__ short8 ldfrag(const unsigned short* p) {
  return *(const short8*)p;
}
__device__ __forceinline__ short8 negbf8(short8 a) {
  union { short8 s; unsigned u[4]; } v; v.s = a;
  #pragma unroll
  for (int q = 0; q < 4; ++q) v.u[q] ^= 0x80008000u;
  return v.s;
}
__device__ __forceinline__ f32x4 mm3(short8 Ah, short8 Al, short8 Bh, short8 Bl, f32x4 acc) {
  acc = __builtin_amdgcn_mfma_f32_16x16x32_bf16(Ah, Bh, acc, 0, 0, 0);
  acc = __builtin_amdgcn_mfma_f32_16x16x32_bf16(Al, Bh, acc, 0, 0, 0);
  acc = __builtin_amdgcn_mfma_f32_16x16x32_bf16(Ah, Bl, acc, 0, 0, 0);
  return acc;
}
__device__ __forceinline__ void packfrag(const float* v, short8& hi, short8& lo) {
  union { short8 s; unsigned short e[8]; } H, L;
  #pragma unroll
  for (int q = 0; q < 8; ++q) split2(v[q], H.e[q], L.e[q]);
  hi = H.s; lo = L.s;
}
// R11-verified paired-u32 fragment load (hi|lo<<16) via v_perm
__device__ __forceinline__ void ldfrag_paired(const unsigned* p, short8& hi, short8& lo) {
  uint4 wa = *(const uint4*)p;
  uint4 wb = *(const uint4*)(p + 4);
  union { short8 s; unsigned u[4]; } H, L;
  H.u[0] = __builtin_amdgcn_perm(wa.y, wa.x, 0x05040100u);
  H.u[1] = __builtin_amdgcn_perm(wa.w, wa.z, 0x05040100u);
  H.u[2] = __builtin_amdgcn_perm(wb.y, wb.x, 0x05040100u);
  H.u[3] = __builtin_amdgcn_perm(wb.w, wb.z, 0x05040100u);
  L.u[0] = __builtin_amdgcn_perm(wa.y, wa.x, 0x07060302u);
  L.u[1] = __builtin_amdgcn_perm(wa.w, wa.z, 0x07060302u);
  L.u[2] = __builtin_amdgcn_perm(wb.y, wb.x, 0x07060302u);
  L.u[3] = __builtin_amdgcn_perm(wb.w, wb.z, 0x07060302u);
  hi = H.s; lo = L.s;
}

__global__ __launch_bounds__(384, 1)
void lindblad_evolve(const void* __restrict__ g_params,
                     const void* __restrict__ g_H0re, const void* __restrict__ g_H0im,
                     const void* __restrict__ g_Hcre, const void* __restrict__ g_Hcim,
                     const void* __restrict__ g_Lre,  const void* __restrict__ g_Lim,
                     const void* __restrict__ g_r0re, const void* __restrict__ g_r0im,
                     float* __restrict__ g_out)
{
  __shared__ __align__(16) unsigned short sPh[16*BST], sPl[16*BST];         // rho^T' hi/lo
  __shared__ __align__(16) unsigned sTp[KL][16*TST];                        // T'_k paired u32
  __shared__ __align__(16) unsigned short sLh[KL][16*BST], sLl[KL][16*BST]; // L'_k
  __shared__ __align__(16) float sMr[16*FST],  sMi[16*FST];                 // M normal layout
  __shared__ __align__(16) float sMrT[16*FST], sMiT[16*FST];                // M transposed layout
  __shared__ __align__(16) float sU[NTS][NC];
  __shared__ __align__(16) float sPops[NTS*DIM];  // pops; first 2560 f32 = setup G-scratch
  __shared__ int sFlag;

  const int tid = threadIdx.x;       // 0..383 (6 waves)
  const int b   = blockIdx.x;
  const int wv  = tid >> 6;          // 0,1: M+G | 2,3: T pairs | 4,5: J+update
  const int ln  = tid & 63;
  const int fm  = ln & 15;
  const int fq  = ln >> 4;
  const int row0 = fq * 4;
  const int fOff  = fm*BST + fq*8;
  const int fOffS = fm*BST + ((fq*8 + 16) & 31);

  // ---- input storage-dtype detection (R1/R2-verified) ----
  if (tid == 0) sFlag = 0;
  __syncthreads();
  if (tid < 256) {
    float v = b2f(((const __hip_bfloat16*)g_H0re)[tid]);
    if (!(fabsf(v) <= 1e10f)) atomicOr(&sFlag, 1);
  }
  __syncthreads();
  const bool isf32 = (sFlag != 0);

  // ---- B-spline control pulses ----
  {
    float kn[20];
    kn[0] = 0.f; kn[1] = 0.f; kn[2] = 0.f;
    #pragma unroll
    for (int q = 0; q < 14; ++q) kn[3 + q] = (float)q / 13.0f;
    kn[17] = 1.f; kn[18] = 1.f; kn[19] = 1.f;
    for (int ts = tid; ts < NTS; ts += 384) {
      const float t = (float)ts * DTF;
      float B[19];
      #pragma unroll
      for (int q = 0; q < 19; ++q) B[q] = (kn[q] <= t && t < kn[q+1]) ? 1.f : 0.f;
      #pragma unroll
      for (int d = 1; d <= 3; ++d) {
        #pragma unroll
        for (int q = 0; q + d < 19; ++q) {
          float ld = kn[q+d]   - kn[q];
          float rd = kn[q+d+1] - kn[q+1];
          float lv = (ld > 0.f) ? (t - kn[q])     / ld * B[q]   : 0.f;
          float rv = (rd > 0.f) ? (kn[q+d+1] - t) / rd * B[q+1] : 0.f;
          B[q] = lv + rv;
        }
      }
      #pragma unroll
      for (int c = 0; c < NC; ++c) {
        float s = 0.f;
        #pragma unroll
        for (int q = 0; q < NPAR; ++q) s += B[q] * ldval(g_params, q*NC + c, isf32);
        sU[ts][c] = s;
      }
    }
  }

  // ---- constants staging (threads 0..255, elementwise (i,j)) ----
  if (tid < 256) {
    float* scr = sPops;   // planes: 0=G0r 1=G0i 2+2c=Gc_r 3+2c=Gc_i
    const int i = tid >> 4, j = tid & 15;
    const int ij = i*16 + j, ji = j*16 + i;
    float h0r = 0.5f * (ldval(g_H0re, ij, isf32) + ldval(g_H0re, ji, isf32));
    float h0i = 0.5f * (ldval(g_H0im, ij, isf32) - ldval(g_H0im, ji, isf32));
    float ldr = 0.f, ldi = 0.f;
    for (int k = 0; k < KL; ++k) {
      #pragma unroll
      for (int m = 0; m < DIM; ++m) {
        float ar = ldval(g_Lre, k*256 + m*16 + i, isf32), ai = ldval(g_Lim, k*256 + m*16 + i, isf32);
        float br = ldval(g_Lre, k*256 + m*16 + j, isf32), bi = ldval(g_Lim, k*256 + m*16 + j, isf32);
        ldr += ar*br + ai*bi;
        ldi += ar*bi - ai*br;
      }
    }
    scr[0*256 + ij] =  h0i - 0.5f*ldr;   // G0r
    scr[1*256 + ij] = -h0r - 0.5f*ldi;   // G0i
    #pragma unroll
    for (int c = 0; c < NC; ++c) {
      float hr = 0.5f * (ldval(g_Hcre, c*256 + ij, isf32) + ldval(g_Hcre, c*256 + ji, isf32));
      float hi = 0.5f * (ldval(g_Hcim, c*256 + ij, isf32) - ldval(g_Hcim, c*256 + ji, isf32));
      scr[(2 + 2*c)*256 + ij] =  hi;
      scr[(3 + 2*c)*256 + ij] = -hr;
    }
    // L': RNE hi/lo split
    #pragma unroll
    for (int k = 0; k < KL; ++k) {
      float lr = ldval(g_Lre, k*256 + ij, isf32);
      float li = ldval(g_Lim, k*256 + ij, isf32);
      unsigned short h;
      h = f2bf(lr); sLh[k][i*BST + j]      = h; sLl[k][i*BST + j]      = f2bf(lr - bf2f(h));
      h = f2bf(li); sLh[k][i*BST + 16 + j] = h; sLl[k][i*BST + 16 + j] = f2bf(li - bf2f(h));
    }
    // rho^T'(0)
    float r0 = ldval(g_r0re, b*256 + ij, isf32);
    float m0 = ldval(g_r0im, b*256 + ij, isf32);
    unsigned short h, l;
    split2(r0, h, l); sPh[j*BST + i]      = h; sPl[j*BST + i]      = l;
    split2(m0, h, l); sPh[j*BST + 16 + i] = h; sPl[j*BST + 16 + i] = l;
  }

  __syncthreads();   // scratch, sL, sP, sU visible

  // ---- per-wave preloads ----
  short8 Ah, Al, A1h, A1l;          // wv0/1: G frag (rebuilt) | wv2/3: L_k, L_{k+1}
  short8 JBh[KL], JBl[KL];          // wv4: straight; wv5: swap+neg
  float  G0v[8], Gcv[NC][8];        // wv0/1
  float  rm[4] = {0.f,0.f,0.f,0.f}; // wv4: rho_re; wv5: rho_im (C-layout)

  if (wv < 2) {
    const int comp = (fq < 2) ? 0 : 1;
    const int base = (fq & 1) * 8;
    const float* scr = sPops;
    {
      const float* s0 = &scr[comp*256 + fm*16 + base];
      f32x4 va = *(const f32x4*)s0, vb = *(const f32x4*)(s0 + 4);
      #pragma unroll
      for (int q = 0; q < 4; ++q) { G0v[q] = va[q]; G0v[4+q] = vb[q]; }
    }
    #pragma unroll
    for (int c = 0; c < NC; ++c) {
      const float* s0 = &scr[(2 + 2*c + comp)*256 + fm*16 + base];
      f32x4 va = *(const f32x4*)s0, vb = *(const f32x4*)(s0 + 4);
      #pragma unroll
      for (int q = 0; q < 4; ++q) { Gcv[c][q] = va[q]; Gcv[c][4+q] = vb[q]; }
    }
    f32x4 uv = *(const f32x4*)&sU[0][0];
    float gv[8];
    #pragma unroll
    for (int q = 0; q < 8; ++q)
      gv[q] = G0v[q] + uv[0]*Gcv[0][q] + uv[1]*Gcv[1][q] + uv[2]*Gcv[2][q] + uv[3]*Gcv[3][q];
    packfrag(gv, Ah, Al);
  } else if (wv < 4) {
    const int k0 = (wv - 2) * 2;    // wv2: L0,L1 ; wv3: L2,L3
    Ah  = ldfrag(&sLh[k0][fOff]);   Al  = ldfrag(&sLl[k0][fOff]);
    A1h = ldfrag(&sLh[k0+1][fOff]); A1l = ldfrag(&sLl[k0+1][fOff]);
  } else if (wv == 4) {
    #pragma unroll
    for (int k = 0; k < KL; ++k) { JBh[k] = ldfrag(&sLh[k][fOff]); JBl[k] = ldfrag(&sLl[k][fOff]); }
    #pragma unroll
    for (int q = 0; q < 4; ++q) rm[q] = ldval(g_r0re, b*256 + (row0+q)*16 + fm, isf32);
  } else {
    #pragma unroll
    for (int k = 0; k < KL; ++k) {
      short8 h = ldfrag(&sLh[k][fOffS]);
      short8 l = ldfrag(&sLl[k][fOffS]);
      if (fq < 2) { h = negbf8(h); l = negbf8(l); }
      JBh[k] = h; JBl[k] = l;
    }
    #pragma unroll
    for (int q = 0; q < 4; ++q) rm[q] = ldval(g_r0im, b*256 + (row0+q)*16 + fm, isf32);
  }

  // ---- main Euler loop: 2 barriers/step ----
  #pragma unroll 1
  for (int t = 0; t < NTS; ++t) {
    __syncthreads();   // B1: sP(t) visible

    if (wv < 2) {
      // ---- M component: wv0 -> Mr (Br), wv1 -> Mi (Bi) ----
      short8 Bh, Bl;
      if (wv == 0) {
        Bh = ldfrag(&sPh[fOff]);  Bl = ldfrag(&sPl[fOff]);
        if (fq >= 2) { Bh = negbf8(Bh); Bl = negbf8(Bl); }
      } else {
        Bh = ldfrag(&sPh[fOffS]); Bl = ldfrag(&sPl[fOffS]);
      }
      f32x4 a = {0.f,0.f,0.f,0.f};
      a = mm3(Ah, Al, Bh, Bl, a);
      float* Mn = (wv == 0) ? sMr  : sMi;
      float* Mt = (wv == 0) ? sMrT : sMiT;
      #pragma unroll
      for (int r = 0; r < 4; ++r) Mn[(row0 + r)*FST + fm] = a[r];
      *(f32x4*)&Mt[fm*FST + row0] = a;
      // rebuild G'(t+1)
      const int tn = (t + 1 < NTS) ? (t + 1) : t;
      f32x4 uv = *(const f32x4*)&sU[tn][0];
      float gv[8];
      #pragma unroll
      for (int q = 0; q < 8; ++q)
        gv[q] = G0v[q] + uv[0]*Gcv[0][q] + uv[1]*Gcv[1][q] + uv[2]*Gcv[2][q] + uv[3]*Gcv[3][q];
      packfrag(gv, Ah, Al);
    } else if (wv < 4) {
      // ---- T pair producer: wv2 -> T0,T1 ; wv3 -> T2,T3 (both components each) ----
      const int k0 = (wv - 2) * 2;
      short8 Brh = ldfrag(&sPh[fOff]),  Brl = ldfrag(&sPl[fOff]);
      if (fq >= 2) { Brh = negbf8(Brh); Brl = negbf8(Brl); }
      short8 Bih = ldfrag(&sPh[fOffS]), Bil = ldfrag(&sPl[fOffS]);
      f32x4 t0r = {0.f,0.f,0.f,0.f}, t0i = {0.f,0.f,0.f,0.f},
            t1r = {0.f,0.f,0.f,0.f}, t1i = {0.f,0.f,0.f,0.f};
      t0r = mm3(Ah,  Al,  Brh, Brl, t0r);
      t1r = mm3(A1h, A1l, Brh, Brl, t1r);
      t0i = mm3(Ah,  Al,  Bih, Bil, t0i);
      t1i = mm3(A1h, A1l, Bih, Bil, t1i);
      #pragma unroll
      for (int r = 0; r < 4; ++r) {
        sTp[k0  ][(row0 + r)*TST + fm]      = splitpack(t0r[r]);
        sTp[k0  ][(row0 + r)*TST + 16 + fm] = splitpack(t0i[r]);
        sTp[k0+1][(row0 + r)*TST + fm]      = splitpack(t1r[r]);
        sTp[k0+1][(row0 + r)*TST + 16 + fm] = splitpack(t1i[r]);
      }
    }
    // wv4/5: idle in phase 1

    __syncthreads();   // B2: sT, sM visible

    if (wv >= 4) {
      // ---- J + update: wv4 -> re (Jr), wv5 -> im (Ji) ----
      short8 T0h, T0l, T1h, T1l, T2h, T2l, T3h, T3l;
      ldfrag_paired(&sTp[0][fm*TST + fq*8], T0h, T0l);
      ldfrag_paired(&sTp[1][fm*TST + fq*8], T1h, T1l);
      ldfrag_paired(&sTp[2][fm*TST + fq*8], T2h, T2l);
      ldfrag_paired(&sTp[3][fm*TST + fq*8], T3h, T3l);
      f32x4 a0 = {0.f,0.f,0.f,0.f}, a1 = {0.f,0.f,0.f,0.f},
            a2 = {0.f,0.f,0.f,0.f}, a3 = {0.f,0.f,0.f,0.f};
      a0 = mm3(T0h, T0l, JBh[0], JBl[0], a0);
      a1 = mm3(T1h, T1l, JBh[1], JBl[1], a1);
      a2 = mm3(T2h, T2l, JBh[2], JBl[2], a2);
      a3 = mm3(T3h, T3l, JBh[3], JBl[3], a3);
      const float* Mt = (wv == 4) ? sMrT : sMiT;
      const float* Mn = (wv == 4) ? sMr  : sMi;
      f32x4 d1 = *(const f32x4*)&Mt[fm*FST + row0];   // M[row0+q][fm] (straight)
      f32x4 d2 = *(const f32x4*)&Mn[fm*FST + row0];   // M[fm][row0+q] (transpose)
      union { short4v s; unsigned short e[4]; } HH, LL;
      if (wv == 4) {
        #pragma unroll
        for (int q = 0; q < 4; ++q) {
          rm[q] += DTF * (d1[q] + d2[q] + ((a0[q] + a1[q]) + (a2[q] + a3[q])));
          split2(rm[q], HH.e[q], LL.e[q]);
        }
        *(short4v*)&sPh[fm*BST + row0] = HH.s;
        *(short4v*)&sPl[fm*BST + row0] = LL.s;
        if ((unsigned)(fm - row0) < 4u) sPops[t*DIM + fm] = rm[fm - row0];
      } else {
        #pragma unroll
        for (int q = 0; q < 4; ++q) {
          rm[q] += DTF * (d1[q] - d2[q] + ((a0[q] + a1[q]) + (a2[q] + a3[q])));
          split2(rm[q], HH.e[q], LL.e[q]);
        }
        *(short4v*)&sPh[fm*BST + 16 + row0] = HH.s;
        *(short4v*)&sPl[fm*BST + 16 + row0] = LL.s;
      }
    }
  }

  // ---- final coalesced pops flush (float4) ----
  __syncthreads();
  for (int idx4 = tid; idx4 < NTS*DIM/4; idx4 += 384) {
    int idx = idx4 * 4;                          // idx = t*16 + d, d 4-aligned
    int tt = idx >> 4, dd = idx & 15;
    *(float4*)&g_out[tt*(BATCH*DIM) + b*DIM + dd] = *(const float4*)&sPops[idx];
  }
}

extern "C" void kernel_launch(void* const* d_in, const int* in_sizes, int n_in,
                              void* d_out, int out_size, void* d_ws, size_t ws_size,
                              hipStream_t stream) {
  (void)out_size; (void)d_ws; (void)ws_size;
  const void *P, *H0r, *H0i, *Hcr, *Hci, *Lr, *Li, *R0r, *R0i;
  int idx64 = -1;
  for (int q = 0; q < n_in; ++q) if (in_sizes[q] == 64) idx64 = q;
  if (idx64 == 6) {   // alphabetical fallback
    H0i = d_in[0]; H0r = d_in[1];
    Hci = d_in[2]; Hcr = d_in[3];
    Li  = d_in[4]; Lr  = d_in[5];
    P   = d_in[6];
    R0i = d_in[7]; R0r = d_in[8];
  } else {            // documented setup_inputs() dict order (R4-verified)
    P   = d_in[0];
    H0r = d_in[1]; H0i = d_in[2];
    Hcr = d_in[3]; Hci = d_in[4];
    Lr  = d_in[5]; Li  = d_in[6];
    R0r = d_in[7]; R0i = d_in[8];
  }
  lindblad_evolve<<<dim3(BATCH), dim3(384), 0, stream>>>(
      P, H0r, H0i, Hcr, Hci, Lr, Li, R0r, R0i, (float*)d_out);
}

// Round 14
// 477.033 us; speedup vs baseline: 1.2117x; 1.0865x over previous
//
#include <hip/hip_runtime.h>
#include <hip/hip_bf16.h>

#define DIM    16
#define BATCH  32
#define KL     4
#define NTS    512
#define NC     4
#define NPAR   16
#define DTF    (1.0f/512.0f)
#define BST    40     // bf16 operand row stride (ushort)
#define FST    20     // f32 tile row stride

using short8  = __attribute__((ext_vector_type(8))) short;
using short4v = __attribute__((ext_vector_type(4))) short;
using f32x4   = __attribute__((ext_vector_type(4))) float;

__device__ __forceinline__ float b2f(__hip_bfloat16 x) { return __bfloat162float(x); }

__device__ __forceinline__ float ldval(const void* p, int idx, bool isf32) {
  return isf32 ? ((const float*)p)[idx]
               : __bfloat162float(((const __hip_bfloat16*)p)[idx]);
}
__device__ __forceinline__ unsigned short f2bf(float x) {   // RNE (setup/L only)
  unsigned u = __float_as_uint(x);
  unsigned r = u + 0x7FFFu + ((u >> 16) & 1u);
  return (unsigned short)(r >> 16);
}
__device__ __forceinline__ float bf2f(unsigned short h) {
  return __uint_as_float(((unsigned)h) << 16);
}
// trunc-trunc hi/lo split (R10-verified)
__device__ __forceinline__ void split2(float v, unsigned short& h, unsigned short& l) {
  unsigned u = __float_as_uint(v);
  h = (unsigned short)(u >> 16);
  float r = v - __uint_as_float(u & 0xFFFF0000u);
  l = (unsigned short)(__float_as_uint(r) >> 16);
}
__device__ __forceinline__ short8 ldfrag(const unsigned short* p) {
  return *(const short8*)p;
}
__device__ __forceinline__ short8 negbf8(short8 a) {
  union { short8 s; unsigned u[4]; } v; v.s = a;
  #pragma unroll
  for (int q = 0; q < 4; ++q) v.u[q] ^= 0x80008000u;
  return v.s;
}
__device__ __forceinline__ f32x4 mm3(short8 Ah, short8 Al, short8 Bh, short8 Bl, f32x4 acc) {
  acc = __builtin_amdgcn_mfma_f32_16x16x32_bf16(Ah, Bh, acc, 0, 0, 0);
  acc = __builtin_amdgcn_mfma_f32_16x16x32_bf16(Al, Bh, acc, 0, 0, 0);
  acc = __builtin_amdgcn_mfma_f32_16x16x32_bf16(Ah, Bl, acc, 0, 0, 0);
  return acc;
}
__device__ __forceinline__ void packfrag(const float* v, short8& hi, short8& lo) {
  union { short8 s; unsigned short e[8]; } H, L;
  #pragma unroll
  for (int q = 0; q < 8; ++q) split2(v[q], H.e[q], L.e[q]);
  hi = H.s; lo = L.s;
}

__global__ __launch_bounds__(512, 1)
void lindblad_evolve(const void* __restrict__ g_params,
                     const void* __restrict__ g_H0re, const void* __restrict__ g_H0im,
                     const void* __restrict__ g_Hcre, const void* __restrict__ g_Hcim,
                     const void* __restrict__ g_Lre,  const void* __restrict__ g_Lim,
                     const void* __restrict__ g_r0re, const void* __restrict__ g_r0im,
                     float* __restrict__ g_out)
{
  __shared__ __align__(16) unsigned short sPh[16*BST], sPl[16*BST];         // rho^T' hi/lo
  __shared__ __align__(16) unsigned short sTh[KL][16*BST], sTl[KL][16*BST]; // T'_k
  __shared__ __align__(16) unsigned short sLh[KL][16*BST], sLl[KL][16*BST]; // L'_k
  __shared__ __align__(16) float sMr[16*FST],  sMi[16*FST];                 // M normal layout
  __shared__ __align__(16) float sMrT[16*FST], sMiT[16*FST];                // M transposed
  __shared__ __align__(16) float sJT[4][16*FST];  // J partials (transposed): 0,1=Jr  2,3=Ji
  __shared__ __align__(16) float sU[NTS][NC];
  __shared__ __align__(16) float sPops[NTS*DIM];  // pops; first 2560 f32 = setup G-scratch
  __shared__ int sFlag;

  const int tid = threadIdx.x;       // 0..511 (8 waves)
  const int b   = blockIdx.x;
  const int wv  = tid >> 6;
  const int ln  = tid & 63;
  const int fm  = ln & 15;
  const int fq  = ln >> 4;
  const int row0 = fq * 4;
  const int fOff  = fm*BST + fq*8;
  const int fOffS = fm*BST + ((fq*8 + 16) & 31);

  // ---- input storage-dtype detection (R1/R2-verified) ----
  if (tid == 0) sFlag = 0;
  __syncthreads();
  if (tid < 256) {
    float v = b2f(((const __hip_bfloat16*)g_H0re)[tid]);
    if (!(fabsf(v) <= 1e10f)) atomicOr(&sFlag, 1);
  }
  __syncthreads();
  const bool isf32 = (sFlag != 0);

  // ---- B-spline control pulses (512 threads: one pass) ----
  {
    float kn[20];
    kn[0] = 0.f; kn[1] = 0.f; kn[2] = 0.f;
    #pragma unroll
    for (int q = 0; q < 14; ++q) kn[3 + q] = (float)q / 13.0f;
    kn[17] = 1.f; kn[18] = 1.f; kn[19] = 1.f;
    const float t = (float)tid * DTF;
    float B[19];
    #pragma unroll
    for (int q = 0; q < 19; ++q) B[q] = (kn[q] <= t && t < kn[q+1]) ? 1.f : 0.f;
    #pragma unroll
    for (int d = 1; d <= 3; ++d) {
      #pragma unroll
      for (int q = 0; q + d < 19; ++q) {
        float ld = kn[q+d]   - kn[q];
        float rd = kn[q+d+1] - kn[q+1];
        float lv = (ld > 0.f) ? (t - kn[q])     / ld * B[q]   : 0.f;
        float rv = (rd > 0.f) ? (kn[q+d+1] - t) / rd * B[q+1] : 0.f;
        B[q] = lv + rv;
      }
    }
    #pragma unroll
    for (int c = 0; c < NC; ++c) {
      float s = 0.f;
      #pragma unroll
      for (int q = 0; q < NPAR; ++q) s += B[q] * ldval(g_params, q*NC + c, isf32);
      sU[tid][c] = s;
    }
  }

  // ---- constants staging (threads 0..255, elementwise (i,j)) ----
  if (tid < 256) {
    float* scr = sPops;   // planes: 0=G0r 1=G0i 2+2c=Gc_r 3+2c=Gc_i
    const int i = tid >> 4, j = tid & 15;
    const int ij = i*16 + j, ji = j*16 + i;
    float h0r = 0.5f * (ldval(g_H0re, ij, isf32) + ldval(g_H0re, ji, isf32));
    float h0i = 0.5f * (ldval(g_H0im, ij, isf32) - ldval(g_H0im, ji, isf32));
    float ldr = 0.f, ldi = 0.f;
    for (int k = 0; k < KL; ++k) {
      #pragma unroll
      for (int m = 0; m < DIM; ++m) {
        float ar = ldval(g_Lre, k*256 + m*16 + i, isf32), ai = ldval(g_Lim, k*256 + m*16 + i, isf32);
        float br = ldval(g_Lre, k*256 + m*16 + j, isf32), bi = ldval(g_Lim, k*256 + m*16 + j, isf32);
        ldr += ar*br + ai*bi;
        ldi += ar*bi - ai*br;
      }
    }
    scr[0*256 + ij] =  h0i - 0.5f*ldr;   // G0r
    scr[1*256 + ij] = -h0r - 0.5f*ldi;   // G0i
    #pragma unroll
    for (int c = 0; c < NC; ++c) {
      float hr = 0.5f * (ldval(g_Hcre, c*256 + ij, isf32) + ldval(g_Hcre, c*256 + ji, isf32));
      float hi = 0.5f * (ldval(g_Hcim, c*256 + ij, isf32) - ldval(g_Hcim, c*256 + ji, isf32));
      scr[(2 + 2*c)*256 + ij] =  hi;
      scr[(3 + 2*c)*256 + ij] = -hr;
    }
    // L': RNE hi/lo split
    #pragma unroll
    for (int k = 0; k < KL; ++k) {
      float lr = ldval(g_Lre, k*256 + ij, isf32);
      float li = ldval(g_Lim, k*256 + ij, isf32);
      unsigned short h;
      h = f2bf(lr); sLh[k][i*BST + j]      = h; sLl[k][i*BST + j]      = f2bf(lr - bf2f(h));
      h = f2bf(li); sLh[k][i*BST + 16 + j] = h; sLl[k][i*BST + 16 + j] = f2bf(li - bf2f(h));
    }
    // rho^T'(0)
    float r0 = ldval(g_r0re, b*256 + ij, isf32);
    float m0 = ldval(g_r0im, b*256 + ij, isf32);
    unsigned short h, l;
    split2(r0, h, l); sPh[j*BST + i]      = h; sPl[j*BST + i]      = l;
    split2(m0, h, l); sPh[j*BST + 16 + i] = h; sPl[j*BST + 16 + i] = l;
  }

  __syncthreads();   // scratch, sL, sP, sU visible

  // ---- per-wave preloads ----
  // P1 tiles: wv0: Mr+T3r | wv1: Mi+T3i | wv2: T0r | wv3: T0i | wv4: T1r | wv5: T1i | wv6: T2r | wv7: T2i
  // P2 (J partials): wv2: Jr k01 | wv3: Ji k01 | wv4: Jr k23 | wv5: Ji k23
  // P3: wv6: re-update | wv7: im-update | wv0/1: G-rebuild
  short8 Ah, Al;                    // P1 A-op: wv0/1 = G (rebuilt); wv2-7 = L_{(wv>>1)-1}
  short8 A2h, A2l;                  // wv0/1 only: L3 fragment
  short8 JBh[2], JBl[2];            // wv2-5: J B-operands
  float  G0v[8], Gcv[NC][8];        // wv0/1
  float  rm[4] = {0.f,0.f,0.f,0.f}; // wv6: rho_re; wv7: rho_im (C-layout)

  if (wv < 2) {
    const int comp = (fq < 2) ? 0 : 1;
    const int base = (fq & 1) * 8;
    const float* scr = sPops;
    {
      const float* s0 = &scr[comp*256 + fm*16 + base];
      f32x4 va = *(const f32x4*)s0, vb = *(const f32x4*)(s0 + 4);
      #pragma unroll
      for (int q = 0; q < 4; ++q) { G0v[q] = va[q]; G0v[4+q] = vb[q]; }
    }
    #pragma unroll
    for (int c = 0; c < NC; ++c) {
      const float* s0 = &scr[(2 + 2*c + comp)*256 + fm*16 + base];
      f32x4 va = *(const f32x4*)s0, vb = *(const f32x4*)(s0 + 4);
      #pragma unroll
      for (int q = 0; q < 4; ++q) { Gcv[c][q] = va[q]; Gcv[c][4+q] = vb[q]; }
    }
    f32x4 uv = *(const f32x4*)&sU[0][0];
    float gv[8];
    #pragma unroll
    for (int q = 0; q < 8; ++q)
      gv[q] = G0v[q] + uv[0]*Gcv[0][q] + uv[1]*Gcv[1][q] + uv[2]*Gcv[2][q] + uv[3]*Gcv[3][q];
    packfrag(gv, Ah, Al);
    A2h = ldfrag(&sLh[3][fOff]);    // L3 for the T3 tile
    A2l = ldfrag(&sLl[3][fOff]);
  } else {
    const int kA = (wv >> 1) - 1;   // wv2,3 -> L0 ; wv4,5 -> L1 ; wv6,7 -> L2
    Ah = ldfrag(&sLh[kA][fOff]);
    Al = ldfrag(&sLl[kA][fOff]);
    if (wv < 6) {
      const int k0 = (wv < 4) ? 0 : 2;
      if ((wv & 1) == 0) {          // Jr partial: straight L' (R7-verified)
        JBh[0] = ldfrag(&sLh[k0][fOff]);   JBl[0] = ldfrag(&sLl[k0][fOff]);
        JBh[1] = ldfrag(&sLh[k0+1][fOff]); JBl[1] = ldfrag(&sLl[k0+1][fOff]);
      } else {                      // Ji partial: swap+neg (R7-verified)
        #pragma unroll
        for (int kk = 0; kk < 2; ++kk) {
          short8 h = ldfrag(&sLh[k0+kk][fOffS]);
          short8 l = ldfrag(&sLl[k0+kk][fOffS]);
          if (fq < 2) { h = negbf8(h); l = negbf8(l); }
          JBh[kk] = h; JBl[kk] = l;
        }
      }
    }
    if (wv == 6) {
      #pragma unroll
      for (int q = 0; q < 4; ++q) rm[q] = ldval(g_r0re, b*256 + (row0+q)*16 + fm, isf32);
    } else if (wv == 7) {
      #pragma unroll
      for (int q = 0; q < 4; ++q) rm[q] = ldval(g_r0im, b*256 + (row0+q)*16 + fm, isf32);
    }
  }

  // ---- main Euler loop: 3 barriers/step, flat per-wave work ----
  #pragma unroll 1
  for (int t = 0; t < NTS; ++t) {
    __syncthreads();   // B1: sP(t) visible, G regs ready

    // ---- P1: 10 product tiles ----
    {
      short8 Bh, Bl;
      if ((wv & 1) == 0) {          // r-type tiles use Br = straight, neg fq>=2
        Bh = ldfrag(&sPh[fOff]);  Bl = ldfrag(&sPl[fOff]);
        if (fq >= 2) { Bh = negbf8(Bh); Bl = negbf8(Bl); }
      } else {                      // i-type tiles use Bi = half-swapped
        Bh = ldfrag(&sPh[fOffS]); Bl = ldfrag(&sPl[fOffS]);
      }
      if (wv < 2) {
        f32x4 aM = {0.f,0.f,0.f,0.f}, aT = {0.f,0.f,0.f,0.f};
        aM = mm3(Ah, Al, Bh, Bl, aM);     // M component
        aT = mm3(A2h, A2l, Bh, Bl, aT);   // T3 component
        float* Mn = (wv == 0) ? sMr  : sMi;
        float* Mt = (wv == 0) ? sMrT : sMiT;
        #pragma unroll
        for (int r = 0; r < 4; ++r) Mn[(row0 + r)*FST + fm] = aM[r];
        *(f32x4*)&Mt[fm*FST + row0] = aM;
        const int co = (wv == 0) ? 0 : 16;
        #pragma unroll
        for (int r = 0; r < 4; ++r) {
          unsigned short h, l;
          split2(aT[r], h, l);
          sTh[3][(row0 + r)*BST + co + fm] = h;
          sTl[3][(row0 + r)*BST + co + fm] = l;
        }
      } else {
        const int kT = (wv >> 1) - 1;
        const int co = (wv & 1) ? 16 : 0;
        f32x4 aT = {0.f,0.f,0.f,0.f};
        aT = mm3(Ah, Al, Bh, Bl, aT);
        #pragma unroll
        for (int r = 0; r < 4; ++r) {
          unsigned short h, l;
          split2(aT[r], h, l);
          sTh[kT][(row0 + r)*BST + co + fm] = h;
          sTl[kT][(row0 + r)*BST + co + fm] = l;
        }
      }
    }

    __syncthreads();   // B2: sT, sM visible

    // ---- P2: J partials on wv2-5 ----
    if (wv >= 2 && wv < 6) {
      const int k0 = (wv < 4) ? 0 : 2;
      short8 TaH = ldfrag(&sTh[k0][fOff]),   TaL = ldfrag(&sTl[k0][fOff]);
      short8 TbH = ldfrag(&sTh[k0+1][fOff]), TbL = ldfrag(&sTl[k0+1][fOff]);
      f32x4 pa = {0.f,0.f,0.f,0.f}, pb = {0.f,0.f,0.f,0.f};
      pa = mm3(TaH, TaL, JBh[0], JBl[0], pa);
      pb = mm3(TbH, TbL, JBh[1], JBl[1], pb);
      f32x4 p;
      #pragma unroll
      for (int q = 0; q < 4; ++q) p[q] = pa[q] + pb[q];   // same association as R10 (a0+a1)
      const int pd = ((wv & 1) << 1) | ((wv >> 2) & 1);   // wv2:0 wv3:2 wv4:1 wv5:3
      *(f32x4*)&sJT[pd][fm*FST + row0] = p;               // transposed layout
    }

    __syncthreads();   // B3: partials visible

    // ---- P3: update (wv6/7); G-rebuild (wv0/1) ----
    if (wv == 6) {
      f32x4 d1  = *(const f32x4*)&sMrT[fm*FST + row0];    // Mr[row0+q][fm]
      f32x4 d2  = *(const f32x4*)&sMr [fm*FST + row0];    // Mr[fm][row0+q]
      f32x4 p01 = *(const f32x4*)&sJT[0][fm*FST + row0];
      f32x4 p23 = *(const f32x4*)&sJT[1][fm*FST + row0];
      union { short4v s; unsigned short e[4]; } HH, LL;
      #pragma unroll
      for (int q = 0; q < 4; ++q) {
        rm[q] += DTF * (d1[q] + d2[q] + (p01[q] + p23[q]));
        split2(rm[q], HH.e[q], LL.e[q]);
      }
      *(short4v*)&sPh[fm*BST + row0] = HH.s;
      *(short4v*)&sPl[fm*BST + row0] = LL.s;
      if ((unsigned)(fm - row0) < 4u) sPops[t*DIM + fm] = rm[fm - row0];
    } else if (wv == 7) {
      f32x4 d1  = *(const f32x4*)&sMiT[fm*FST + row0];
      f32x4 d2  = *(const f32x4*)&sMi [fm*FST + row0];
      f32x4 p01 = *(const f32x4*)&sJT[2][fm*FST + row0];
      f32x4 p23 = *(const f32x4*)&sJT[3][fm*FST + row0];
      union { short4v s; unsigned short e[4]; } HH, LL;
      #pragma unroll
      for (int q = 0; q < 4; ++q) {
        rm[q] += DTF * (d1[q] - d2[q] + (p01[q] + p23[q]));
        split2(rm[q], HH.e[q], LL.e[q]);
      }
      *(short4v*)&sPh[fm*BST + 16 + row0] = HH.s;
      *(short4v*)&sPl[fm*BST + 16 + row0] = LL.s;
    } else if (wv < 2) {
      // rebuild G'(t+1) fragment in the otherwise-idle P3 slot
      const int tn = (t + 1 < NTS) ? (t + 1) : t;
      f32x4 uv = *(const f32x4*)&sU[tn][0];
      float gv[8];
      #pragma unroll
      for (int q = 0; q < 8; ++q)
        gv[q] = G0v[q] + uv[0]*Gcv[0][q] + uv[1]*Gcv[1][q] + uv[2]*Gcv[2][q] + uv[3]*Gcv[3][q];
      packfrag(gv, Ah, Al);
    }
  }

  // ---- final coalesced pops flush (float4) ----
  __syncthreads();
  #pragma unroll
  for (int s = 0; s < NTS*DIM/(512*4); ++s) {
    int idx = (s*512 + tid) * 4;                 // idx = t*16 + d, d 4-aligned
    int tt = idx >> 4, dd = idx & 15;
    *(float4*)&g_out[tt*(BATCH*DIM) + b*DIM + dd] = *(const float4*)&sPops[idx];
  }
}

extern "C" void kernel_launch(void* const* d_in, const int* in_sizes, int n_in,
                              void* d_out, int out_size, void* d_ws, size_t ws_size,
                              hipStream_t stream) {
  (void)out_size; (void)d_ws; (void)ws_size;
  const void *P, *H0r, *H0i, *Hcr, *Hci, *Lr, *Li, *R0r, *R0i;
  int idx64 = -1;
  for (int q = 0; q < n_in; ++q) if (in_sizes[q] == 64) idx64 = q;
  if (idx64 == 6) {   // alphabetical fallback
    H0i = d_in[0]; H0r = d_in[1];
    Hci = d_in[2]; Hcr = d_in[3];
    Li  = d_in[4]; Lr  = d_in[5];
    P   = d_in[6];
    R0i = d_in[7]; R0r = d_in[8];
  } else {            // documented setup_inputs() dict order (R4-verified)
    P   = d_in[0];
    H0r = d_in[1]; H0i = d_in[2];
    Hcr = d_in[3]; Hci = d_in[4];
    Lr  = d_in[5]; Li  = d_in[6];
    R0r = d_in[7]; R0i = d_in[8];
  }
  lindblad_evolve<<<dim3(BATCH), dim3(512), 0, stream>>>(
      P, H0r, H0i, Hcr, Hci, Lr, Li, R0r, R0i, (float*)d_out);
}

// Round 15
// 416.899 us; speedup vs baseline: 1.3864x; 1.1442x over previous
//
#include <hip/hip_runtime.h>
#include <hip/hip_bf16.h>

#define DIM    16
#define BATCH  32
#define KL     4
#define NTS    512
#define NC     4
#define NPAR   16
#define DTF    (1.0f/512.0f)
#define BST    40     // bf16 operand row stride (ushort)
#define FST    20     // f32 tile row stride

using short8  = __attribute__((ext_vector_type(8))) short;
using short4v = __attribute__((ext_vector_type(4))) short;
using f32x4   = __attribute__((ext_vector_type(4))) float;

__device__ __forceinline__ float b2f(__hip_bfloat16 x) { return __bfloat162float(x); }

__device__ __forceinline__ float ldval(const void* p, int idx, bool isf32) {
  return isf32 ? ((const float*)p)[idx]
               : __bfloat162float(((const __hip_bfloat16*)p)[idx]);
}
__device__ __forceinline__ unsigned short f2bf(float x) {   // RNE (setup/L only)
  unsigned u = __float_as_uint(x);
  unsigned r = u + 0x7FFFu + ((u >> 16) & 1u);
  return (unsigned short)(r >> 16);
}
__device__ __forceinline__ float bf2f(unsigned short h) {
  return __uint_as_float(((unsigned)h) << 16);
}
// trunc-trunc hi/lo split (R10-verified)
__device__ __forceinline__ void split2(float v, unsigned short& h, unsigned short& l) {
  unsigned u = __float_as_uint(v);
  h = (unsigned short)(u >> 16);
  float r = v - __uint_as_float(u & 0xFFFF0000u);
  l = (unsigned short)(__float_as_uint(r) >> 16);
}
__device__ __forceinline__ short8 ldfrag(const unsigned short* p) {
  return *(const short8*)p;
}
__device__ __forceinline__ short8 negbf8(short8 a) {
  union { short8 s; unsigned u[4]; } v; v.s = a;
  #pragma unroll
  for (int q = 0; q < 4; ++q) v.u[q] ^= 0x80008000u;
  return v.s;
}
__device__ __forceinline__ f32x4 mm3(short8 Ah, short8 Al, short8 Bh, short8 Bl, f32x4 acc) {
  acc = __builtin_amdgcn_mfma_f32_16x16x32_bf16(Ah, Bh, acc, 0, 0, 0);
  acc = __builtin_amdgcn_mfma_f32_16x16x32_bf16(Al, Bh, acc, 0, 0, 0);
  acc = __builtin_amdgcn_mfma_f32_16x16x32_bf16(Ah, Bl, acc, 0, 0, 0);
  return acc;
}
__device__ __forceinline__ void packfrag(const float* v, short8& hi, short8& lo) {
  union { short8 s; unsigned short e[8]; } H, L;
  #pragma unroll
  for (int q = 0; q < 8; ++q) split2(v[q], H.e[q], L.e[q]);
  hi = H.s; lo = L.s;
}

__global__ __launch_bounds__(512, 1)
void lindblad_evolve(const void* __restrict__ g_params,
                     const void* __restrict__ g_H0re, const void* __restrict__ g_H0im,
                     const void* __restrict__ g_Hcre, const void* __restrict__ g_Hcim,
                     const void* __restrict__ g_Lre,  const void* __restrict__ g_Lim,
                     const void* __restrict__ g_r0re, const void* __restrict__ g_r0im,
                     float* __restrict__ g_out)
{
  __shared__ __align__(16) unsigned short sPh[16*BST], sPl[16*BST];         // rho^T' hi/lo
  __shared__ __align__(16) unsigned short sTh[KL][16*BST], sTl[KL][16*BST]; // T_k row-major [Tr|Ti]
  __shared__ __align__(16) unsigned short sLh[KL][16*BST], sLl[KL][16*BST]; // L'_k
  __shared__ __align__(16) float sMr[16*FST],  sMi[16*FST];   // M normal layout
  __shared__ __align__(16) float sMrT[16*FST], sMiT[16*FST];  // M transposed layout
  __shared__ __align__(16) float sU[NTS][NC];
  __shared__ __align__(16) float sPops[NTS*DIM];  // pops; first 2560 f32 = setup G-scratch
  __shared__ int sFlag;

  const int tid = threadIdx.x;       // 0..511 (8 waves)
  const int b   = blockIdx.x;
  const int wv  = tid >> 6;          // 0,1: M | 2-5: T_k (transpose path) | 6,7: J+update
  const int ln  = tid & 63;
  const int fm  = ln & 15;
  const int fq  = ln >> 4;
  const int row0 = fq * 4;
  const int fOff  = fm*BST + fq*8;
  const int fOffS = fm*BST + ((fq*8 + 16) & 31);

  // ---- input storage-dtype detection (R1/R2-verified) ----
  if (tid == 0) sFlag = 0;
  __syncthreads();
  if (tid < 256) {
    float v = b2f(((const __hip_bfloat16*)g_H0re)[tid]);
    if (!(fabsf(v) <= 1e10f)) atomicOr(&sFlag, 1);
  }
  __syncthreads();
  const bool isf32 = (sFlag != 0);

  // ---- B-spline control pulses (512 threads: one pass) ----
  {
    float kn[20];
    kn[0] = 0.f; kn[1] = 0.f; kn[2] = 0.f;
    #pragma unroll
    for (int q = 0; q < 14; ++q) kn[3 + q] = (float)q / 13.0f;
    kn[17] = 1.f; kn[18] = 1.f; kn[19] = 1.f;
    const float t = (float)tid * DTF;
    float B[19];
    #pragma unroll
    for (int q = 0; q < 19; ++q) B[q] = (kn[q] <= t && t < kn[q+1]) ? 1.f : 0.f;
    #pragma unroll
    for (int d = 1; d <= 3; ++d) {
      #pragma unroll
      for (int q = 0; q + d < 19; ++q) {
        float ld = kn[q+d]   - kn[q];
        float rd = kn[q+d+1] - kn[q+1];
        float lv = (ld > 0.f) ? (t - kn[q])     / ld * B[q]   : 0.f;
        float rv = (rd > 0.f) ? (kn[q+d+1] - t) / rd * B[q+1] : 0.f;
        B[q] = lv + rv;
      }
    }
    #pragma unroll
    for (int c = 0; c < NC; ++c) {
      float s = 0.f;
      #pragma unroll
      for (int q = 0; q < NPAR; ++q) s += B[q] * ldval(g_params, q*NC + c, isf32);
      sU[tid][c] = s;
    }
  }

  // ---- constants staging (threads 0..255, elementwise (i,j)) ----
  if (tid < 256) {
    float* scr = sPops;   // planes: 0=G0r 1=G0i 2+2c=Gc_r 3+2c=Gc_i
    const int i = tid >> 4, j = tid & 15;
    const int ij = i*16 + j, ji = j*16 + i;
    float h0r = 0.5f * (ldval(g_H0re, ij, isf32) + ldval(g_H0re, ji, isf32));
    float h0i = 0.5f * (ldval(g_H0im, ij, isf32) - ldval(g_H0im, ji, isf32));
    float ldr = 0.f, ldi = 0.f;
    for (int k = 0; k < KL; ++k) {
      #pragma unroll
      for (int m = 0; m < DIM; ++m) {
        float ar = ldval(g_Lre, k*256 + m*16 + i, isf32), ai = ldval(g_Lim, k*256 + m*16 + i, isf32);
        float br = ldval(g_Lre, k*256 + m*16 + j, isf32), bi = ldval(g_Lim, k*256 + m*16 + j, isf32);
        ldr += ar*br + ai*bi;
        ldi += ar*bi - ai*br;
      }
    }
    scr[0*256 + ij] =  h0i - 0.5f*ldr;   // G0r
    scr[1*256 + ij] = -h0r - 0.5f*ldi;   // G0i
    #pragma unroll
    for (int c = 0; c < NC; ++c) {
      float hr = 0.5f * (ldval(g_Hcre, c*256 + ij, isf32) + ldval(g_Hcre, c*256 + ji, isf32));
      float hi = 0.5f * (ldval(g_Hcim, c*256 + ij, isf32) - ldval(g_Hcim, c*256 + ji, isf32));
      scr[(2 + 2*c)*256 + ij] =  hi;
      scr[(3 + 2*c)*256 + ij] = -hr;
    }
    // L': RNE hi/lo split
    #pragma unroll
    for (int k = 0; k < KL; ++k) {
      float lr = ldval(g_Lre, k*256 + ij, isf32);
      float li = ldval(g_Lim, k*256 + ij, isf32);
      unsigned short h;
      h = f2bf(lr); sLh[k][i*BST + j]      = h; sLl[k][i*BST + j]      = f2bf(lr - bf2f(h));
      h = f2bf(li); sLh[k][i*BST + 16 + j] = h; sLl[k][i*BST + 16 + j] = f2bf(li - bf2f(h));
    }
    // rho^T'(0)
    float r0 = ldval(g_r0re, b*256 + ij, isf32);
    float m0 = ldval(g_r0im, b*256 + ij, isf32);
    unsigned short h, l;
    split2(r0, h, l); sPh[j*BST + i]      = h; sPl[j*BST + i]      = l;
    split2(m0, h, l); sPh[j*BST + 16 + i] = h; sPl[j*BST + 16 + i] = l;
  }

  __syncthreads();   // scratch, sL, sP, sU visible

  // ---- per-wave preloads ----
  short8 Ah, Al;                    // wv0/1: G frag (rebuilt per step)
  short8 TrBh, TrBl, TiBh, TiBl;    // wv2-5: T^T B-operands (L-derived constants)
  short8 JBh[KL], JBl[KL];          // wv6: straight Lf; wv7: swap+neg (R10 contents)
  float  G0v[8], Gcv[NC][8];        // wv0/1
  float  rm[4] = {0.f,0.f,0.f,0.f}; // wv6: rho_re; wv7: rho_im (C-layout)

  if (wv < 2) {
    const int comp = (fq < 2) ? 0 : 1;
    const int base = (fq & 1) * 8;
    const float* scr = sPops;
    {
      const float* s0 = &scr[comp*256 + fm*16 + base];
      f32x4 va = *(const f32x4*)s0, vb = *(const f32x4*)(s0 + 4);
      #pragma unroll
      for (int q = 0; q < 4; ++q) { G0v[q] = va[q]; G0v[4+q] = vb[q]; }
    }
    #pragma unroll
    for (int c = 0; c < NC; ++c) {
      const float* s0 = &scr[(2 + 2*c + comp)*256 + fm*16 + base];
      f32x4 va = *(const f32x4*)s0, vb = *(const f32x4*)(s0 + 4);
      #pragma unroll
      for (int q = 0; q < 4; ++q) { Gcv[c][q] = va[q]; Gcv[c][4+q] = vb[q]; }
    }
    f32x4 uv = *(const f32x4*)&sU[0][0];
    float gv[8];
    #pragma unroll
    for (int q = 0; q < 8; ++q)
      gv[q] = G0v[q] + uv[0]*Gcv[0][q] + uv[1]*Gcv[1][q] + uv[2]*Gcv[2][q] + uv[3]*Gcv[3][q];
    packfrag(gv, Ah, Al);
  } else if (wv < 6) {
    // T^T path constants for k = wv-2:
    //  Tr^T = [rho_r^T|rho_i^T](A, straight) x [Lr^T; -Li^T](B) -> B = Lf with neg fq>=2
    //  Ti^T = [rho_i^T|rho_r^T](A, swapped)  x [Lr^T;  Li^T](B) -> B = Lf straight
    const int k = wv - 2;
    TiBh = ldfrag(&sLh[k][fOff]);
    TiBl = ldfrag(&sLl[k][fOff]);
    TrBh = (fq >= 2) ? negbf8(TiBh) : TiBh;
    TrBl = (fq >= 2) ? negbf8(TiBl) : TiBl;
  } else if (wv == 6) {
    // Jr^T = [Lr|Li](A) x [Tr^T; Ti^T](B) -> A = straight Lf (same as R10 wv6 JB)
    #pragma unroll
    for (int k = 0; k < KL; ++k) { JBh[k] = ldfrag(&sLh[k][fOff]); JBl[k] = ldfrag(&sLl[k][fOff]); }
    #pragma unroll
    for (int q = 0; q < 4; ++q) rm[q] = ldval(g_r0re, b*256 + (row0+q)*16 + fm, isf32);
  } else {
    // Ji^T = [-Li|Lr](A) x [Tr^T; Ti^T](B) -> A = swap+neg (same as R10 wv7 JB)
    #pragma unroll
    for (int k = 0; k < KL; ++k) {
      short8 h = ldfrag(&sLh[k][fOffS]);
      short8 l = ldfrag(&sLl[k][fOffS]);
      if (fq < 2) { h = negbf8(h); l = negbf8(l); }
      JBh[k] = h; JBl[k] = l;
    }
    #pragma unroll
    for (int q = 0; q < 4; ++q) rm[q] = ldval(g_r0im, b*256 + (row0+q)*16 + fm, isf32);
  }

  // ---- main Euler loop: 2 barriers/step (R10 skeleton) ----
  #pragma unroll 1
  for (int t = 0; t < NTS; ++t) {
    __syncthreads();   // B1: sP(t) visible

    if (wv < 2) {
      // ---- M component (R10-exact path): wv0 -> Mr, wv1 -> Mi ----
      short8 Bh, Bl;
      if (wv == 0) {
        Bh = ldfrag(&sPh[fOff]);  Bl = ldfrag(&sPl[fOff]);
        if (fq >= 2) { Bh = negbf8(Bh); Bl = negbf8(Bl); }
      } else {
        Bh = ldfrag(&sPh[fOffS]); Bl = ldfrag(&sPl[fOffS]);
      }
      f32x4 a = {0.f,0.f,0.f,0.f};
      a = mm3(Ah, Al, Bh, Bl, a);
      float* Mn = (wv == 0) ? sMr  : sMi;
      float* Mt = (wv == 0) ? sMrT : sMiT;
      #pragma unroll
      for (int r = 0; r < 4; ++r) Mn[(row0 + r)*FST + fm] = a[r];
      *(f32x4*)&Mt[fm*FST + row0] = a;
      // (G-rebuild moved to the phase-2 idle slot)
    } else if (wv < 6) {
      // ---- T^T producer: A = rho-frags (no negs), B = L-consts; b64 row writes ----
      const int k = wv - 2;
      short8 Arh = ldfrag(&sPh[fOff]),  Arl = ldfrag(&sPl[fOff]);    // [rho_r^T|rho_i^T]
      short8 Aih = ldfrag(&sPh[fOffS]), Ail = ldfrag(&sPl[fOffS]);   // [rho_i^T|rho_r^T]
      f32x4 tr = {0.f,0.f,0.f,0.f}, ti = {0.f,0.f,0.f,0.f};
      tr = mm3(Arh, Arl, TrBh, TrBl, tr);    // Tr^T tile
      ti = mm3(Aih, Ail, TiBh, TiBl, ti);    // Ti^T tile
      // C-layout lane owns Tr^T[row0+r][fm] = Tr[fm][row0+r] -> contiguous row write
      union { short4v s; unsigned short e[4]; } HR, LR, HI, LI;
      #pragma unroll
      for (int r = 0; r < 4; ++r) {
        split2(tr[r], HR.e[r], LR.e[r]);
        split2(ti[r], HI.e[r], LI.e[r]);
      }
      *(short4v*)&sTh[k][fm*BST + row0]      = HR.s;
      *(short4v*)&sTl[k][fm*BST + row0]      = LR.s;
      *(short4v*)&sTh[k][fm*BST + 16 + row0] = HI.s;
      *(short4v*)&sTl[k][fm*BST + 16 + row0] = LI.s;
    }
    // wv6/7: idle in phase 1

    __syncthreads();   // B2: sT, sM visible

    if (wv >= 6) {
      // ---- J^T + update: wv6 -> Jr^T (= Jr, symmetric), wv7 -> Ji^T (= -Ji) ----
      short8 T0h = ldfrag(&sTh[0][fOff]), T0l = ldfrag(&sTl[0][fOff]);
      short8 T1h = ldfrag(&sTh[1][fOff]), T1l = ldfrag(&sTl[1][fOff]);
      short8 T2h = ldfrag(&sTh[2][fOff]), T2l = ldfrag(&sTl[2][fOff]);
      short8 T3h = ldfrag(&sTh[3][fOff]), T3l = ldfrag(&sTl[3][fOff]);
      f32x4 a0 = {0.f,0.f,0.f,0.f}, a1 = {0.f,0.f,0.f,0.f},
            a2 = {0.f,0.f,0.f,0.f}, a3 = {0.f,0.f,0.f,0.f};
      a0 = mm3(JBh[0], JBl[0], T0h, T0l, a0);   // A = L-const, B = T-frag
      a1 = mm3(JBh[1], JBl[1], T1h, T1l, a1);
      a2 = mm3(JBh[2], JBl[2], T2h, T2l, a2);
      a3 = mm3(JBh[3], JBl[3], T3h, T3l, a3);
      const float* Mt = (wv == 6) ? sMrT : sMiT;
      const float* Mn = (wv == 6) ? sMr  : sMi;
      f32x4 d1 = *(const f32x4*)&Mt[fm*FST + row0];   // M[row0+q][fm]
      f32x4 d2 = *(const f32x4*)&Mn[fm*FST + row0];   // M[fm][row0+q]
      union { short4v s; unsigned short e[4]; } HH, LL;
      if (wv == 6) {
        #pragma unroll
        for (int q = 0; q < 4; ++q) {
          rm[q] += DTF * (d1[q] + d2[q] + ((a0[q] + a1[q]) + (a2[q] + a3[q])));
          split2(rm[q], HH.e[q], LL.e[q]);
        }
        *(short4v*)&sPh[fm*BST + row0] = HH.s;
        *(short4v*)&sPl[fm*BST + row0] = LL.s;
        if ((unsigned)(fm - row0) < 4u) sPops[t*DIM + fm] = rm[fm - row0];
      } else {
        #pragma unroll
        for (int q = 0; q < 4; ++q) {
          // computed = Ji^T = -Ji at own element -> subtract
          rm[q] += DTF * (d1[q] - d2[q] - ((a0[q] + a1[q]) + (a2[q] + a3[q])));
          split2(rm[q], HH.e[q], LL.e[q]);
        }
        *(short4v*)&sPh[fm*BST + 16 + row0] = HH.s;
        *(short4v*)&sPl[fm*BST + 16 + row0] = LL.s;
      }
    } else if (wv < 2) {
      // ---- G-rebuild in the otherwise-idle phase-2 slot (registers only) ----
      const int tn = (t + 1 < NTS) ? (t + 1) : t;
      f32x4 uv = *(const f32x4*)&sU[tn][0];
      float gv[8];
      #pragma unroll
      for (int q = 0; q < 8; ++q)
        gv[q] = G0v[q] + uv[0]*Gcv[0][q] + uv[1]*Gcv[1][q] + uv[2]*Gcv[2][q] + uv[3]*Gcv[3][q];
      packfrag(gv, Ah, Al);
    }
  }

  // ---- final coalesced pops flush (float4) ----
  __syncthreads();
  #pragma unroll
  for (int s = 0; s < NTS*DIM/(512*4); ++s) {
    int idx = (s*512 + tid) * 4;                 // idx = t*16 + d, d 4-aligned
    int tt = idx >> 4, dd = idx & 15;
    *(float4*)&g_out[tt*(BATCH*DIM) + b*DIM + dd] = *(const float4*)&sPops[idx];
  }
}

extern "C" void kernel_launch(void* const* d_in, const int* in_sizes, int n_in,
                              void* d_out, int out_size, void* d_ws, size_t ws_size,
                              hipStream_t stream) {
  (void)out_size; (void)d_ws; (void)ws_size;
  const void *P, *H0r, *H0i, *Hcr, *Hci, *Lr, *Li, *R0r, *R0i;
  int idx64 = -1;
  for (int q = 0; q < n_in; ++q) if (in_sizes[q] == 64) idx64 = q;
  if (idx64 == 6) {   // alphabetical fallback
    H0i = d_in[0]; H0r = d_in[1];
    Hci = d_in[2]; Hcr = d_in[3];
    Li  = d_in[4]; Lr  = d_in[5];
    P   = d_in[6];
    R0i = d_in[7]; R0r = d_in[8];
  } else {            // documented setup_inputs() dict order (R4-verified)
    P   = d_in[0];
    H0r = d_in[1]; H0i = d_in[2];
    Hcr = d_in[3]; Hci = d_in[4];
    Lr  = d_in[5]; Li  = d_in[6];
    R0r = d_in[7]; R0i = d_in[8];
  }
  lindblad_evolve<<<dim3(BATCH), dim3(512), 0, stream>>>(
      P, H0r, H0i, Hcr, Hci, Lr, Li, R0r, R0i, (float*)d_out);
}